// Round 1
// baseline (216.550 us; speedup 1.0000x reference)
//
#include <hip/hip_runtime.h>

// YOLO loss: 5-scalar reduction over N*S*S cells.
// d_in[0] pred_tensor  f32 [N,S,S,30]
// d_in[1] target_boxes f32 [N,S,S,4]
// d_in[2] target_cls   f32 [N,S,S,20]
// d_in[3] has_object_map bool -> int32 [N,S,S]
// d_out: (total, reg, contain, noobj, cls) f32[5]

namespace {
constexpr int   kCh    = 30;         // B*5 + NUM_CLS
constexpr int   kCls   = 20;
constexpr float kLCoord = 5.0f;
constexpr float kLNoobj = 0.5f;
constexpr float kInvS   = 1.0f / 14.0f;
}

__global__ void yolo_zero5(float* out) {
  if (threadIdx.x < 5) out[threadIdx.x] = 0.0f;
}

__global__ __launch_bounds__(256) void yolo_loss_kernel(
    const float* __restrict__ pred,
    const float* __restrict__ tbox,
    const float* __restrict__ tcls,
    const int*   __restrict__ mask,
    float* __restrict__ out,
    int ncells)
{
  const int idx = blockIdx.x * blockDim.x + threadIdx.x;

  float cls_l = 0.f, noobj_l = 0.f, reg_l = 0.f, cont_l = 0.f;

  if (idx < ncells) {
    const float* p = pred + (long)idx * kCh;
    // first 10 floats: 2 boxes x (x,y,w,h,conf). base is 8B-aligned (120B/cell).
    float pb[10];
    const float2* p2 = reinterpret_cast<const float2*>(p);
#pragma unroll
    for (int i = 0; i < 5; ++i) {
      float2 t = p2[i];
      pb[2 * i] = t.x;
      pb[2 * i + 1] = t.y;
    }

    const bool m = (mask[idx] != 0);

    if (!m) {
      // no-object: only confidence penalty (L_NOOBJ applied at the end)
      noobj_l = pb[4] * pb[4] + pb[9] * pb[9];
    } else {
      // ---- class loss: sum over 20 classes (pred_cls - target_cls)^2 ----
      const float2* pc2 = reinterpret_cast<const float2*>(p + 10);  // 8B-aligned
      const float4* tc4 = reinterpret_cast<const float4*>(tcls + (long)idx * kCls);  // 16B-aligned
#pragma unroll
      for (int i = 0; i < 5; ++i) {
        float4 t  = tc4[i];
        float2 a0 = pc2[2 * i];
        float2 a1 = pc2[2 * i + 1];
        float c0 = a0.x - t.x;
        float c1 = a0.y - t.y;
        float c2 = a1.x - t.z;
        float c3 = a1.y - t.w;
        cls_l += c0 * c0 + c1 * c1 + c2 * c2 + c3 * c3;
      }

      // ---- IoU of both predicted boxes vs target ----
      float4 tb = *reinterpret_cast<const float4*>(tbox + (long)idx * 4);  // 16B-aligned
      float tcx = tb.x * kInvS, tcy = tb.y * kInvS;
      float tx1 = tcx - 0.5f * tb.z;
      float ty1 = tcy - 0.5f * tb.w;
      float tx2 = tcx + 0.5f * tb.z;
      float ty2 = tcy + 0.5f * tb.w;
      float ta  = (tx2 - tx1) * (ty2 - ty1);

      float iou0, iou1;
#pragma unroll
      for (int b = 0; b < 2; ++b) {
        float qx = pb[5 * b + 0], qy = pb[5 * b + 1];
        float qw = pb[5 * b + 2], qh = pb[5 * b + 3];
        float cx = qx * kInvS, cy = qy * kInvS;
        float px1 = cx - 0.5f * qw, py1 = cy - 0.5f * qh;
        float px2 = cx + 0.5f * qw, py2 = cy + 0.5f * qh;
        float lx = fmaxf(px1, tx1), ly = fmaxf(py1, ty1);
        float rx = fminf(px2, tx2), ry = fminf(py2, ty2);
        float w = fmaxf(rx - lx, 0.f), h = fmaxf(ry - ly, 0.f);
        float inter = w * h;
        float pa = (px2 - px1) * (py2 - py1);
        float v = inter / (pa + ta - inter);
        if (b == 0) iou0 = v; else iou1 = v;
      }

      // argmax -> first max on tie, so box1 only on STRICT greater
      const bool sel = (iou1 > iou0);
      float biou = fmaxf(iou0, iou1);
      float bx = sel ? pb[5] : pb[0];
      float by = sel ? pb[6] : pb[1];
      float bw = sel ? pb[7] : pb[2];
      float bh = sel ? pb[8] : pb[3];
      float bc = sel ? pb[9] : pb[4];

      // reg uses RAW cx,cy (not /S) per reference
      float dx = bx - tb.x, dy = by - tb.y;
      float dw = sqrtf(bw) - sqrtf(tb.z);
      float dh = sqrtf(bh) - sqrtf(tb.w);
      reg_l  = dx * dx + dy * dy + dw * dw + dh * dh;  // xL_COORD at the end

      float dc = bc - biou;
      cont_l = dc * dc;
    }
  }

  // ---- wave64 reduction ----
#pragma unroll
  for (int off = 32; off > 0; off >>= 1) {
    cls_l   += __shfl_down(cls_l,   off, 64);
    noobj_l += __shfl_down(noobj_l, off, 64);
    reg_l   += __shfl_down(reg_l,   off, 64);
    cont_l  += __shfl_down(cont_l,  off, 64);
  }

  __shared__ float red[4][4];
  const int lane = threadIdx.x & 63;
  const int wid  = threadIdx.x >> 6;
  if (lane == 0) {
    red[wid][0] = cls_l;
    red[wid][1] = noobj_l;
    red[wid][2] = reg_l;
    red[wid][3] = cont_l;
  }
  __syncthreads();

  if (threadIdx.x == 0) {
    float c = 0.f, n = 0.f, r = 0.f, t = 0.f;
#pragma unroll
    for (int w = 0; w < 4; ++w) {
      c += red[w][0];
      n += red[w][1];
      r += red[w][2];
      t += red[w][3];
    }
    n *= kLNoobj;
    r *= kLCoord;
    atomicAdd(&out[0], c + n + r + t);  // total
    atomicAdd(&out[1], r);              // reg_loss
    atomicAdd(&out[2], t);              // contain_loss
    atomicAdd(&out[3], n);              // no_obj_loss
    atomicAdd(&out[4], c);              // cls_loss
  }
}

extern "C" void kernel_launch(void* const* d_in, const int* in_sizes, int n_in,
                              void* d_out, int out_size, void* d_ws, size_t ws_size,
                              hipStream_t stream) {
  const float* pred = (const float*)d_in[0];
  const float* tbox = (const float*)d_in[1];
  const float* tcls = (const float*)d_in[2];
  const int*   mask = (const int*)d_in[3];
  float* out = (float*)d_out;

  const int ncells = in_sizes[3];  // N*S*S

  yolo_zero5<<<1, 64, 0, stream>>>(out);

  const int block = 256;
  const int grid  = (ncells + block - 1) / block;
  yolo_loss_kernel<<<grid, block, 0, stream>>>(pred, tbox, tcls, mask, out, ncells);
}

// Round 2
// 38.059 us; speedup vs baseline: 5.6898x; 5.6898x over previous
//
#include <hip/hip_runtime.h>

// YOLO loss: 5-scalar reduction over N*S*S cells. Two-stage reduction:
//   stage 1: grid-stride per-cell partials -> per-block sums in d_ws (plain stores)
//   stage 2: one block reduces partials, applies weights, writes d_out[5]
// (R1 lesson: 15,680 same-cache-line atomicAdds serialized = 219 us. No atomics now.)
//
// d_in[0] pred_tensor  f32 [N,S,S,30]
// d_in[1] target_boxes f32 [N,S,S,4]
// d_in[2] target_cls   f32 [N,S,S,20]
// d_in[3] has_object_map bool -> int32 [N,S,S]
// d_out: (total, reg, contain, noobj, cls) f32[5]

namespace {
constexpr float kLCoord = 5.0f;
constexpr float kLNoobj = 0.5f;
constexpr float kInvS   = 1.0f / 14.0f;
constexpr int   kBlocks = 1568;   // 1568*256*2 == 802816 cells exactly; grid-stride handles any size
}

__global__ __launch_bounds__(256) void yolo_partial_kernel(
    const float* __restrict__ pred,
    const float* __restrict__ tbox,
    const float* __restrict__ tcls,
    const int*   __restrict__ mask,
    float* __restrict__ ws,
    int ncells)
{
  float cls_l = 0.f, noobj_l = 0.f, reg_l = 0.f, cont_l = 0.f;

  for (int idx = blockIdx.x * blockDim.x + threadIdx.x; idx < ncells;
       idx += gridDim.x * blockDim.x) {
    const float* p = pred + (long)idx * 30;
    // first 10 floats: 2 boxes x (x,y,w,h,conf). 8B-aligned (120 B/cell).
    float pb[10];
    const float2* p2 = reinterpret_cast<const float2*>(p);
#pragma unroll
    for (int i = 0; i < 5; ++i) {
      float2 t = p2[i];
      pb[2 * i]     = t.x;
      pb[2 * i + 1] = t.y;
    }

    const bool m = (mask[idx] != 0);

    if (!m) {
      noobj_l += pb[4] * pb[4] + pb[9] * pb[9];
    } else {
      // ---- class loss ----
      const float2* pc2 = reinterpret_cast<const float2*>(p + 10);
      const float4* tc4 = reinterpret_cast<const float4*>(tcls + (long)idx * 20);
#pragma unroll
      for (int i = 0; i < 5; ++i) {
        float4 t  = tc4[i];
        float2 a0 = pc2[2 * i];
        float2 a1 = pc2[2 * i + 1];
        float c0 = a0.x - t.x;
        float c1 = a0.y - t.y;
        float c2 = a1.x - t.z;
        float c3 = a1.y - t.w;
        cls_l += c0 * c0 + c1 * c1 + c2 * c2 + c3 * c3;
      }

      // ---- IoU of both predicted boxes vs target ----
      float4 tb = *reinterpret_cast<const float4*>(tbox + (long)idx * 4);
      float tcx = tb.x * kInvS, tcy = tb.y * kInvS;
      float tx1 = tcx - 0.5f * tb.z;
      float ty1 = tcy - 0.5f * tb.w;
      float tx2 = tcx + 0.5f * tb.z;
      float ty2 = tcy + 0.5f * tb.w;
      float ta  = (tx2 - tx1) * (ty2 - ty1);

      float iou0, iou1;
#pragma unroll
      for (int b = 0; b < 2; ++b) {
        float qw = pb[5 * b + 2], qh = pb[5 * b + 3];
        float cx = pb[5 * b + 0] * kInvS, cy = pb[5 * b + 1] * kInvS;
        float px1 = cx - 0.5f * qw, py1 = cy - 0.5f * qh;
        float px2 = cx + 0.5f * qw, py2 = cy + 0.5f * qh;
        float lx = fmaxf(px1, tx1), ly = fmaxf(py1, ty1);
        float rx = fminf(px2, tx2), ry = fminf(py2, ty2);
        float w = fmaxf(rx - lx, 0.f), h = fmaxf(ry - ly, 0.f);
        float inter = w * h;
        float pa = (px2 - px1) * (py2 - py1);
        float v = inter / (pa + ta - inter);
        if (b == 0) iou0 = v; else iou1 = v;
      }

      // jnp.argmax -> first max on tie: box1 only on STRICT greater
      const bool sel = (iou1 > iou0);
      float biou = fmaxf(iou0, iou1);
      float bx = sel ? pb[5] : pb[0];
      float by = sel ? pb[6] : pb[1];
      float bw = sel ? pb[7] : pb[2];
      float bh = sel ? pb[8] : pb[3];
      float bc = sel ? pb[9] : pb[4];

      float dx = bx - tb.x, dy = by - tb.y;
      float dw = sqrtf(bw) - sqrtf(tb.z);
      float dh = sqrtf(bh) - sqrtf(tb.w);
      reg_l += dx * dx + dy * dy + dw * dw + dh * dh;  // *L_COORD in stage 2

      float dc = bc - biou;
      cont_l += dc * dc;
    }
  }

  // ---- wave64 reduction ----
#pragma unroll
  for (int off = 32; off > 0; off >>= 1) {
    cls_l   += __shfl_down(cls_l,   off, 64);
    noobj_l += __shfl_down(noobj_l, off, 64);
    reg_l   += __shfl_down(reg_l,   off, 64);
    cont_l  += __shfl_down(cont_l,  off, 64);
  }

  __shared__ float red[4][4];
  const int lane = threadIdx.x & 63;
  const int wid  = threadIdx.x >> 6;
  if (lane == 0) {
    red[wid][0] = cls_l;
    red[wid][1] = noobj_l;
    red[wid][2] = reg_l;
    red[wid][3] = cont_l;
  }
  __syncthreads();

  if (threadIdx.x == 0) {
    float c = 0.f, n = 0.f, r = 0.f, t = 0.f;
#pragma unroll
    for (int w = 0; w < 4; ++w) {
      c += red[w][0];
      n += red[w][1];
      r += red[w][2];
      t += red[w][3];
    }
    float* wp = ws + (long)blockIdx.x * 8;  // 8-float stride: no same-line sharing across blocks... (2 blocks/line, plain stores, fine)
    wp[0] = c;
    wp[1] = n;
    wp[2] = r;
    wp[3] = t;
  }
}

__global__ __launch_bounds__(256) void yolo_final_kernel(
    const float* __restrict__ ws, int nparts, float* __restrict__ out)
{
  float c = 0.f, n = 0.f, r = 0.f, t = 0.f;
  for (int i = threadIdx.x; i < nparts; i += 256) {
    const float* wp = ws + (long)i * 8;
    c += wp[0];
    n += wp[1];
    r += wp[2];
    t += wp[3];
  }

#pragma unroll
  for (int off = 32; off > 0; off >>= 1) {
    c += __shfl_down(c, off, 64);
    n += __shfl_down(n, off, 64);
    r += __shfl_down(r, off, 64);
    t += __shfl_down(t, off, 64);
  }

  __shared__ float red[4][4];
  const int lane = threadIdx.x & 63;
  const int wid  = threadIdx.x >> 6;
  if (lane == 0) {
    red[wid][0] = c;
    red[wid][1] = n;
    red[wid][2] = r;
    red[wid][3] = t;
  }
  __syncthreads();

  if (threadIdx.x == 0) {
    float cc = 0.f, nn = 0.f, rr = 0.f, tt = 0.f;
#pragma unroll
    for (int w = 0; w < 4; ++w) {
      cc += red[w][0];
      nn += red[w][1];
      rr += red[w][2];
      tt += red[w][3];
    }
    nn *= kLNoobj;
    rr *= kLCoord;
    out[0] = cc + nn + rr + tt;  // total
    out[1] = rr;                 // reg_loss
    out[2] = tt;                 // contain_loss
    out[3] = nn;                 // no_obj_loss
    out[4] = cc;                 // cls_loss
  }
}

extern "C" void kernel_launch(void* const* d_in, const int* in_sizes, int n_in,
                              void* d_out, int out_size, void* d_ws, size_t ws_size,
                              hipStream_t stream) {
  const float* pred = (const float*)d_in[0];
  const float* tbox = (const float*)d_in[1];
  const float* tcls = (const float*)d_in[2];
  const int*   mask = (const int*)d_in[3];
  float* out = (float*)d_out;
  float* ws  = (float*)d_ws;

  const int ncells = in_sizes[3];  // N*S*S

  yolo_partial_kernel<<<kBlocks, 256, 0, stream>>>(pred, tbox, tcls, mask, ws, ncells);
  yolo_final_kernel<<<1, 256, 0, stream>>>(ws, kBlocks, out);
}

// Round 3
// 35.339 us; speedup vs baseline: 6.1279x; 1.0770x over previous
//
#include <hip/hip_runtime.h>

// YOLO loss, two-stage reduction, coalesced via LDS tile staging.
// R1 lesson: same-line atomics serialize (219us) -> two-stage plain stores.
// R2 lesson: 120B-stride float2 pred loads = ~8x line-request amplification,
//            latency-bound at 38us. Fix: stage pred tile to LDS with fully
//            coalesced float4 loads; cls-loss loop made element-parallel so
//            tcls is read as per-lane consecutive float4 (20%4==0, no straddle).
//
// d_in[0] pred_tensor  f32 [N,S,S,30]
// d_in[1] target_boxes f32 [N,S,S,4]
// d_in[2] target_cls   f32 [N,S,S,20]
// d_in[3] has_object_map bool -> int32 [N,S,S]
// d_out: (total, reg, contain, noobj, cls) f32[5]

namespace {
constexpr float kLCoord = 5.0f;
constexpr float kLNoobj = 0.5f;
constexpr float kInvS   = 1.0f / 14.0f;
constexpr int   kTile   = 256;    // cells per block
}

__global__ __launch_bounds__(256) void yolo_partial_kernel(
    const float* __restrict__ pred,
    const float* __restrict__ tbox,
    const float* __restrict__ tcls,
    const int*   __restrict__ mask,
    float* __restrict__ ws,
    int ncells)
{
  __shared__ float lds_pred[kTile * 30];   // 30 KB, linear (cell-major, 30 floats/cell)
  __shared__ int   lds_mask[kTile];        // 1 KB
  __shared__ float red[4][4];

  const int tid  = threadIdx.x;
  const int base = blockIdx.x * kTile;
  const int tile_cells = min(kTile, ncells - base);   // 256 except (never here) tail

  float cls_l = 0.f, noobj_l = 0.f, reg_l = 0.f, cont_l = 0.f;

  // ---- Phase A: coalesced staging ----
  const int m_reg = (tid < tile_cells) ? mask[base + tid] : 0;
  lds_mask[tid] = m_reg;

  {
    // pred tile floats: tile_cells*30 ; base*30 is float4-aligned (256*30*4B).
    const float4* src = reinterpret_cast<const float4*>(pred + (long)base * 30);
    float4* dst = reinterpret_cast<float4*>(lds_pred);
    const int nfl = tile_cells * 30;
    const int nf4 = nfl >> 2;                 // 1920 when full
    for (int i = tid; i < nf4; i += 256) dst[i] = src[i];
    // scalar tail (only possible on a partial tile; nfl%4 != 0 case)
    for (int i = (nf4 << 2) + tid; i < nfl; i += 256)
      lds_pred[i] = pred[(long)base * 30 + i];
  }
  __syncthreads();

  // ---- Phase B: per-cell (thread t <-> cell base+t) ----
  if (tid < tile_cells) {
    const float2* lp2 = reinterpret_cast<const float2*>(lds_pred + tid * 30);  // 120B base, 8B aligned
    float pb[10];
#pragma unroll
    for (int i = 0; i < 5; ++i) {
      float2 v = lp2[i];
      pb[2 * i]     = v.x;
      pb[2 * i + 1] = v.y;
    }

    if (!m_reg) {
      noobj_l = pb[4] * pb[4] + pb[9] * pb[9];
    } else {
      // tbox load: thread<->cell contiguous => coalesced float4
      float4 tb = *(reinterpret_cast<const float4*>(tbox) + (long)(base + tid));
      float tcx = tb.x * kInvS, tcy = tb.y * kInvS;
      float tx1 = tcx - 0.5f * tb.z;
      float ty1 = tcy - 0.5f * tb.w;
      float tx2 = tcx + 0.5f * tb.z;
      float ty2 = tcy + 0.5f * tb.w;
      float ta  = (tx2 - tx1) * (ty2 - ty1);

      float iou0, iou1;
#pragma unroll
      for (int b = 0; b < 2; ++b) {
        float qw = pb[5 * b + 2], qh = pb[5 * b + 3];
        float cx = pb[5 * b + 0] * kInvS, cy = pb[5 * b + 1] * kInvS;
        float px1 = cx - 0.5f * qw, py1 = cy - 0.5f * qh;
        float px2 = cx + 0.5f * qw, py2 = cy + 0.5f * qh;
        float lx = fmaxf(px1, tx1), ly = fmaxf(py1, ty1);
        float rx = fminf(px2, tx2), ry = fminf(py2, ty2);
        float w = fmaxf(rx - lx, 0.f), h = fmaxf(ry - ly, 0.f);
        float inter = w * h;
        float pa = (px2 - px1) * (py2 - py1);
        float v = inter / (pa + ta - inter);
        if (b == 0) iou0 = v; else iou1 = v;
      }

      // jnp.argmax -> first max on tie: box1 only on STRICT greater
      const bool sel = (iou1 > iou0);
      float biou = fmaxf(iou0, iou1);
      float bx = sel ? pb[5] : pb[0];
      float by = sel ? pb[6] : pb[1];
      float bw = sel ? pb[7] : pb[2];
      float bh = sel ? pb[8] : pb[3];
      float bc = sel ? pb[9] : pb[4];

      float dx = bx - tb.x, dy = by - tb.y;
      float dw = sqrtf(bw) - sqrtf(tb.z);
      float dh = sqrtf(bh) - sqrtf(tb.w);
      reg_l = dx * dx + dy * dy + dw * dw + dh * dh;   // *L_COORD in stage 2

      float dc = bc - biou;
      cont_l = dc * dc;
    }
  }

  // ---- Phase C: cls loss, element-parallel over the tile's tcls float4s ----
  // f4 index i in [0, tile_cells*5): cell = i/5, channels 10+4*(i%5)..+3.
  // tcls loads: per-lane consecutive float4 => fully coalesced.
  {
    const float4* tc = reinterpret_cast<const float4*>(tcls) + (long)base * 5;
    const int nf4 = tile_cells * 5;           // 1280 when full
#pragma unroll
    for (int k = 0; k < 5; ++k) {
      const int i = tid + (k << 8);
      if (i < nf4) {
        const int cl = i / 5;
        if (lds_mask[cl]) {                   // same-word broadcast across 5 lanes
          float4 t = tc[i];
          const float2* lp2 =
              reinterpret_cast<const float2*>(lds_pred + cl * 30 + 10 + ((i % 5) << 2));
          float2 a0 = lp2[0], a1 = lp2[1];
          float c0 = a0.x - t.x;
          float c1 = a0.y - t.y;
          float c2 = a1.x - t.z;
          float c3 = a1.y - t.w;
          cls_l += c0 * c0 + c1 * c1 + c2 * c2 + c3 * c3;
        }
      }
    }
  }

  // ---- wave64 reduction ----
#pragma unroll
  for (int off = 32; off > 0; off >>= 1) {
    cls_l   += __shfl_down(cls_l,   off, 64);
    noobj_l += __shfl_down(noobj_l, off, 64);
    reg_l   += __shfl_down(reg_l,   off, 64);
    cont_l  += __shfl_down(cont_l,  off, 64);
  }

  const int lane = tid & 63;
  const int wid  = tid >> 6;
  if (lane == 0) {
    red[wid][0] = cls_l;
    red[wid][1] = noobj_l;
    red[wid][2] = reg_l;
    red[wid][3] = cont_l;
  }
  __syncthreads();

  if (tid == 0) {
    float c = 0.f, n = 0.f, r = 0.f, t = 0.f;
#pragma unroll
    for (int w = 0; w < 4; ++w) {
      c += red[w][0];
      n += red[w][1];
      r += red[w][2];
      t += red[w][3];
    }
    float4 v = make_float4(c, n, r, t);
    *(reinterpret_cast<float4*>(ws) + blockIdx.x) = v;
  }
}

__global__ __launch_bounds__(256) void yolo_final_kernel(
    const float* __restrict__ ws, int nparts, float* __restrict__ out)
{
  float c = 0.f, n = 0.f, r = 0.f, t = 0.f;
  for (int i = threadIdx.x; i < nparts; i += 256) {
    float4 v = *(reinterpret_cast<const float4*>(ws) + i);
    c += v.x;
    n += v.y;
    r += v.z;
    t += v.w;
  }

#pragma unroll
  for (int off = 32; off > 0; off >>= 1) {
    c += __shfl_down(c, off, 64);
    n += __shfl_down(n, off, 64);
    r += __shfl_down(r, off, 64);
    t += __shfl_down(t, off, 64);
  }

  __shared__ float red[4][4];
  const int lane = threadIdx.x & 63;
  const int wid  = threadIdx.x >> 6;
  if (lane == 0) {
    red[wid][0] = c;
    red[wid][1] = n;
    red[wid][2] = r;
    red[wid][3] = t;
  }
  __syncthreads();

  if (threadIdx.x == 0) {
    float cc = 0.f, nn = 0.f, rr = 0.f, tt = 0.f;
#pragma unroll
    for (int w = 0; w < 4; ++w) {
      cc += red[w][0];
      nn += red[w][1];
      rr += red[w][2];
      tt += red[w][3];
    }
    nn *= kLNoobj;
    rr *= kLCoord;
    out[0] = cc + nn + rr + tt;  // total
    out[1] = rr;                 // reg_loss
    out[2] = tt;                 // contain_loss
    out[3] = nn;                 // no_obj_loss
    out[4] = cc;                 // cls_loss
  }
}

extern "C" void kernel_launch(void* const* d_in, const int* in_sizes, int n_in,
                              void* d_out, int out_size, void* d_ws, size_t ws_size,
                              hipStream_t stream) {
  const float* pred = (const float*)d_in[0];
  const float* tbox = (const float*)d_in[1];
  const float* tcls = (const float*)d_in[2];
  const int*   mask = (const int*)d_in[3];
  float* out = (float*)d_out;
  float* ws  = (float*)d_ws;

  const int ncells = in_sizes[3];              // N*S*S
  const int grid   = (ncells + kTile - 1) / kTile;

  yolo_partial_kernel<<<grid, 256, 0, stream>>>(pred, tbox, tcls, mask, ws, ncells);
  yolo_final_kernel<<<1, 256, 0, stream>>>(ws, grid, out);
}